// Round 1
// 556.218 us; speedup vs baseline: 1.1364x; 1.1364x over previous
//
#include <hip/hip_runtime.h>
#include <stdint.h>

// Problem constants
#define BB 16384
#define II 512
#define HH 1024
#define OO 512

typedef short s16x8 __attribute__((ext_vector_type(8)));
typedef float f32x4 __attribute__((ext_vector_type(4)));

__device__ __forceinline__ unsigned short f2bf(float x) {
  union { float f; unsigned u; } v; v.f = x;
  return (unsigned short)((v.u + 0x7fffu + ((v.u >> 16) & 1u)) >> 16);  // RNE
}
__device__ __forceinline__ float bf2f(unsigned short b) {
  union { unsigned u; float f; } v; v.u = ((unsigned)b) << 16;
  return v.f;
}
__device__ __forceinline__ float sigmoid_f(float x) {
  return 1.0f / (1.0f + __expf(-x));
}
__device__ __forceinline__ float tanh_f(float x) {
  float ax = fabsf(x);
  float e = __expf(-2.0f * ax);
  float t = (1.0f - e) / (1.0f + e);
  return x >= 0.0f ? t : -t;
}

// async global->LDS, 16B per lane, LDS dest = wave-uniform base + lane*16
__device__ __forceinline__ void stage16(const void* g, void* l) {
  __builtin_amdgcn_global_load_lds((const __attribute__((address_space(1))) void*)g,
                                   (__attribute__((address_space(3))) void*)l,
                                   16, 0, 0);
}

// ---- 128-tile helper (kept for gemm_out) ----
__device__ __forceinline__ void mma_step64(const unsigned short* As, const unsigned short* Bs,
                                           f32x4 acc[4][4], int lane, int wave) {
  const int wm = wave & 1, wn = wave >> 1;
  const int ln = lane & 15, q = lane >> 4;
#pragma unroll
  for (int s = 0; s < 2; ++s) {
    s16x8 af[4], bfr[4];
#pragma unroll
    for (int i = 0; i < 4; ++i) {
      const int r = wm * 64 + i * 16 + ln;
      af[i] = *(const s16x8*)(As + r * 64 + ((((s << 2) + q) + r) & 7) * 8);
    }
#pragma unroll
    for (int i = 0; i < 4; ++i) {
      const int r = wn * 64 + i * 16 + ln;
      bfr[i] = *(const s16x8*)(Bs + r * 64 + ((((s << 2) + q) + r) & 7) * 8);
    }
#pragma unroll
    for (int mi = 0; mi < 4; ++mi)
#pragma unroll
      for (int ni = 0; ni < 4; ++ni)
        acc[mi][ni] = __builtin_amdgcn_mfma_f32_16x16x32_bf16(af[mi], bfr[ni], acc[mi][ni], 0, 0, 0);
  }
}

// ---------------- prep kernels ----------------

__global__ __launch_bounds__(256) void prep_X(const float* __restrict__ inp,
                                              const float* __restrict__ h,
                                              unsigned short* __restrict__ Xb,
                                              unsigned short* __restrict__ Hlo) {
  int t = blockIdx.x * 256 + threadIdx.x;
  int base = t * 8;
  int b = base / 1536;
  int k = base - b * 1536;
  const float* src = (k < 512) ? (inp + b * 512 + k) : (h + b * 1024 + (k - 512));
  float4 v0 = *(const float4*)src;
  float4 v1 = *(const float4*)(src + 4);
  float f[8] = {v0.x, v0.y, v0.z, v0.w, v1.x, v1.y, v1.z, v1.w};
  unsigned short hi[8];
#pragma unroll
  for (int i = 0; i < 8; ++i) hi[i] = f2bf(f[i]);
  *(s16x8*)(Xb + base) = *(s16x8*)hi;
  if (k >= 512) {
    unsigned short lo[8];
#pragma unroll
    for (int i = 0; i < 8; ++i) lo[i] = f2bf(f[i] - bf2f(hi[i]));
    *(s16x8*)(Hlo + b * 1024 + (k - 512)) = *(s16x8*)lo;
  }
}

// Gate weights -> bf16 [4096][1536], K-contiguous, columns permuted for BN=256:
// n = blkX*256 + wn*64 + gate*16 + ln  <->  unit = blkX*64 + wn*16 + ln
__global__ __launch_bounds__(256) void prep_Wg(const float* __restrict__ Wx,
                                               const float* __restrict__ Wh,
                                               unsigned short* __restrict__ Wg) {
  int t = blockIdx.x * 256 + threadIdx.x;
  int base = t * 8;
  int n = base / 1536;
  int k = base - n * 1536;
  int r = n & 255;
  int gate = (r >> 4) & 3;
  int unit = ((n >> 8) << 6) + (((r >> 6) & 3) << 4) + (r & 15);
  const float* src = (k < 512) ? (Wx + (gate * 1024 + unit) * 512 + k)
                               : (Wh + (gate * 1024 + unit) * 1024 + (k - 512));
  float4 v0 = *(const float4*)src;
  float4 v1 = *(const float4*)(src + 4);
  float f[8] = {v0.x, v0.y, v0.z, v0.w, v1.x, v1.y, v1.z, v1.w};
  unsigned short o[8];
#pragma unroll
  for (int i = 0; i < 8; ++i) o[i] = f2bf(f[i]);
  *(s16x8*)(Wg + base) = *(s16x8*)o;
}

// z-correction weights [1024][2048]: k<1024 -> W_lo(Whz), k>=1024 -> W_hi(Whz)
__global__ __launch_bounds__(256) void prep_Wz2(const float* __restrict__ Whz,
                                                unsigned short* __restrict__ Wz2) {
  int t = blockIdx.x * 256 + threadIdx.x;
  int base = t * 8;
  int n = base >> 11;
  int k = base & 2047;
  int klo = (k < 1024) ? k : (k - 1024);
  const float* src = Whz + n * 1024 + klo;
  float4 v0 = *(const float4*)src;
  float4 v1 = *(const float4*)(src + 4);
  float f[8] = {v0.x, v0.y, v0.z, v0.w, v1.x, v1.y, v1.z, v1.w};
  unsigned short o[8];
  if (k < 1024) {
#pragma unroll
    for (int i = 0; i < 8; ++i) { unsigned short h_ = f2bf(f[i]); o[i] = f2bf(f[i] - bf2f(h_)); }
  } else {
#pragma unroll
    for (int i = 0; i < 8; ++i) o[i] = f2bf(f[i]);
  }
  *(s16x8*)(Wz2 + base) = *(s16x8*)o;
}

__global__ __launch_bounds__(256) void prep_Wout(const float* __restrict__ Wout,
                                                 unsigned short* __restrict__ Wo) {
  int t = blockIdx.x * 256 + threadIdx.x;
  int base = t * 8;
  float4 v0 = *(const float4*)(Wout + base);
  float4 v1 = *(const float4*)(Wout + base + 4);
  float f[8] = {v0.x, v0.y, v0.z, v0.w, v1.x, v1.y, v1.z, v1.w};
  unsigned short o[8];
#pragma unroll
  for (int i = 0; i < 8; ++i) o[i] = f2bf(f[i]);
  *(s16x8*)(Wo + base) = *(s16x8*)o;
}

// ================= 256x256 / 8-wave / counted-vmcnt GEMM machinery =================
//
// LDS: lds[buf][A=0/B=1][256*64 bf16]; per row r (mod 8) the logical 16B chunk j
// lives at slot (j+r)&7 (proven conflict-free: current kernel measures 0 conflicts).
// Staging: thread chunk p = u*512+tid -> row u*64+(tid>>3), slot tid&7,
// logical j = ((tid&7)-(tid>>3))&7; LDS dest is wave-uniform base + lane*16.
//
// Schedule per K-tile t (4 phases, quadrants mi-pairs):
//   q0: read all 8 B frags + A frags mi{0,1}; stage A(t+1) h0 -> other buf
//   q1: read A mi{2,3};                       stage A(t+1) h1 -> other buf
//   q2: read A mi{4,5};                       stage B(t+2) h0 -> this buf (B slot freed at q0)
//   q3: read A mi{6,7};                       stage B(t+2) h1 -> this buf; vmcnt(4)
// Each phase: reads; stage; s_barrier; lgkmcnt(0); setprio(1); 16 MFMA; setprio(0); s_barrier.
// vmcnt(4) at q3 leaves exactly B(t+2)h0/h1 (4 loads) in flight and certifies
// A(t+1) (+ all older, incl. B(t+1) staged at t-1.q2/q3) before tile t+1's reads.
// Never vmcnt(0) in the main loop (T4); drain only once at tile NT-2.

#define RD_A(CA, MI, KS) (*(const s16x8*)((CA) + ((KS) ? aoff1 : aoff0) + (MI) * 1024))
#define RD_B(CB, NI, KS) (*(const s16x8*)((CB) + ((KS) ? boff1 : boff0) + (NI) * 1024))
#define VM4 asm volatile("s_waitcnt vmcnt(4)" ::: "memory")
#define VM0 asm volatile("s_waitcnt vmcnt(0)" ::: "memory")
#define VMNONE ((void)0)
#define NOST ((void)0)

#define ST_A(TT, HHX, DB) do { \
  stage16(gA[HHX][0] + (TT) * 64, (DB) + (HHX) * 8192); \
  stage16(gA[HHX][1] + (TT) * 64, (DB) + (HHX) * 8192 + 4096); } while (0)
#define ST_B(TT, HHX, DB) do { \
  stage16(gB[HHX][0] + (TT) * 64, (DB) + (HHX) * 8192); \
  stage16(gB[HHX][1] + (TT) * 64, (DB) + (HHX) * 8192 + 4096); } while (0)
// zcorr A source switches at tile 16 (h_hi from Xb, then h_lo from Hlo)
#define ZST_A(TT, HHX, DB) do { \
  const unsigned short* g0_; const unsigned short* g1_; \
  if ((TT) < 16) { g0_ = gAX[HHX][0] + (TT) * 64; g1_ = gAX[HHX][1] + (TT) * 64; } \
  else           { g0_ = gAH[HHX][0] + ((TT) - 16) * 64; g1_ = gAH[HHX][1] + ((TT) - 16) * 64; } \
  stage16(g0_, (DB) + (HHX) * 8192); \
  stage16(g1_, (DB) + (HHX) * 8192 + 4096); } while (0)

#define PH_MFMA(Q, A00, A01, A10, A11) do { \
  __builtin_amdgcn_s_barrier(); \
  asm volatile("s_waitcnt lgkmcnt(0)" ::: "memory"); \
  __builtin_amdgcn_s_setprio(1); \
  _Pragma("unroll") \
  for (int ni = 0; ni < 4; ++ni) { \
    acc[2 * (Q)    ][ni] = __builtin_amdgcn_mfma_f32_16x16x32_bf16(A00, bq0[ni], acc[2 * (Q)    ][ni], 0, 0, 0); \
    acc[2 * (Q) + 1][ni] = __builtin_amdgcn_mfma_f32_16x16x32_bf16(A01, bq0[ni], acc[2 * (Q) + 1][ni], 0, 0, 0); \
  } \
  _Pragma("unroll") \
  for (int ni = 0; ni < 4; ++ni) { \
    acc[2 * (Q)    ][ni] = __builtin_amdgcn_mfma_f32_16x16x32_bf16(A10, bq1[ni], acc[2 * (Q)    ][ni], 0, 0, 0); \
    acc[2 * (Q) + 1][ni] = __builtin_amdgcn_mfma_f32_16x16x32_bf16(A11, bq1[ni], acc[2 * (Q) + 1][ni], 0, 0, 0); \
  } \
  __builtin_amdgcn_s_setprio(0); \
} while (0)

#define KTILE(CA, CB, S0, S1, S2, S3, VMX) do { \
  s16x8 bq0[4], bq1[4]; \
  _Pragma("unroll") \
  for (int ni = 0; ni < 4; ++ni) { bq0[ni] = RD_B(CB, ni, 0); bq1[ni] = RD_B(CB, ni, 1); } \
  s16x8 a00 = RD_A(CA, 0, 0), a01 = RD_A(CA, 1, 0); \
  s16x8 a10 = RD_A(CA, 0, 1), a11 = RD_A(CA, 1, 1); \
  S0; \
  PH_MFMA(0, a00, a01, a10, a11); \
  __builtin_amdgcn_s_barrier(); \
  a00 = RD_A(CA, 2, 0); a01 = RD_A(CA, 3, 0); a10 = RD_A(CA, 2, 1); a11 = RD_A(CA, 3, 1); \
  S1; \
  PH_MFMA(1, a00, a01, a10, a11); \
  __builtin_amdgcn_s_barrier(); \
  a00 = RD_A(CA, 4, 0); a01 = RD_A(CA, 5, 0); a10 = RD_A(CA, 4, 1); a11 = RD_A(CA, 5, 1); \
  S2; \
  PH_MFMA(2, a00, a01, a10, a11); \
  __builtin_amdgcn_s_barrier(); \
  a00 = RD_A(CA, 6, 0); a01 = RD_A(CA, 7, 0); a10 = RD_A(CA, 6, 1); a11 = RD_A(CA, 7, 1); \
  S3; \
  PH_MFMA(3, a00, a01, a10, a11); \
  VMX; \
  __builtin_amdgcn_s_barrier(); \
} while (0)

// Gate GEMM + fused LSTM epilogue. M=16384, N=4096 (permuted), K=1536, NT=24.
__global__ __launch_bounds__(512, 2) void gemm_gates2(const unsigned short* __restrict__ Xb,
                                                      const unsigned short* __restrict__ Wg,
                                                      const float* __restrict__ bx,
                                                      const float* __restrict__ cold,
                                                      const unsigned short* __restrict__ Dgz,
                                                      float* __restrict__ hnew,
                                                      unsigned short* __restrict__ hnewb) {
  __shared__ unsigned short lds[2][2][16384];   // 128 KiB
  const int tid = threadIdx.x;
  const int lane = tid & 63, wave = tid >> 6;
  const int wm = wave & 1, wn = wave >> 1;
  const int ln = lane & 15, qlane = lane >> 4;
  const int n0 = blockIdx.x << 8, m0 = blockIdx.y << 8;
  const int sr = tid >> 3;
  const int j = ((tid & 7) - (sr & 7)) & 7;

  const unsigned short* gA[2][2];
  const unsigned short* gB[2][2];
#pragma unroll
  for (int hh = 0; hh < 2; ++hh)
#pragma unroll
    for (int u = 0; u < 2; ++u) {
      const int row = hh * 128 + u * 64 + sr;
      gA[hh][u] = Xb + (size_t)(m0 + row) * 1536 + j * 8;
      gB[hh][u] = Wg + (size_t)(n0 + row) * 1536 + j * 8;
    }
  unsigned short* const dA0 = &lds[0][0][0] + (tid & ~63) * 8;
  unsigned short* const dB0 = &lds[0][1][0] + (tid & ~63) * 8;
  unsigned short* const dA1 = &lds[1][0][0] + (tid & ~63) * 8;
  unsigned short* const dB1 = &lds[1][1][0] + (tid & ~63) * 8;
  const unsigned short* const lA0 = &lds[0][0][0];
  const unsigned short* const lB0 = &lds[0][1][0];
  const unsigned short* const lA1 = &lds[1][0][0];
  const unsigned short* const lB1 = &lds[1][1][0];
  const int sl0 = ((qlane + ln) & 7) * 8;
  const int sl1 = sl0 ^ 32;
  const int aoff0 = (wm * 128 + ln) * 64 + sl0;
  const int aoff1 = (wm * 128 + ln) * 64 + sl1;
  const int boff0 = (wn * 64 + ln) * 64 + sl0;
  const int boff1 = (wn * 64 + ln) * 64 + sl1;

  f32x4 acc[8][4] = {};

  // prologue: A(0), B(0), B(1); allow B(1) (4 loads) in flight
  ST_A(0, 0, dA0); ST_A(0, 1, dA0);
  ST_B(0, 0, dB0); ST_B(0, 1, dB0);
  ST_B(1, 0, dB1); ST_B(1, 1, dB1);
  VM4;
  __builtin_amdgcn_s_barrier();

#pragma unroll 1
  for (int t = 0; t < 22; t += 2) {
    KTILE(lA0, lB0, ST_A(t + 1, 0, dA1), ST_A(t + 1, 1, dA1),
                    ST_B(t + 2, 0, dB0), ST_B(t + 2, 1, dB0), VM4);
    KTILE(lA1, lB1, ST_A(t + 2, 0, dA0), ST_A(t + 2, 1, dA0),
                    ST_B(t + 3, 0, dB1), ST_B(t + 3, 1, dB1), VM4);
  }
  KTILE(lA0, lB0, ST_A(23, 0, dA1), ST_A(23, 1, dA1), NOST, NOST, VM0);
  KTILE(lA1, lB1, NOST, NOST, NOST, NOST, VMNONE);

  // Epilogue: acc[mi][ni] is gate ni for unit = blkX*64 + wn*16 + ln.
  const int unit = (blockIdx.x << 6) + (wn << 4) + ln;
  const float bi = bx[unit];
  const float bo = bx[1024 + unit];
  const float bfg = bx[2048 + unit];
  const float bz = bx[3072 + unit];
#pragma unroll
  for (int mi = 0; mi < 8; ++mi) {
#pragma unroll
    for (int r = 0; r < 4; ++r) {
      const int b = m0 + wm * 128 + mi * 16 + qlane * 4 + r;
      const int idx = b * 1024 + unit;
      const float gi = acc[mi][0][r] + bi;
      const float go = acc[mi][1][r] + bo;
      const float gf = acc[mi][2][r] + bfg;
      const float gz = acc[mi][3][r] + bz + bf2f(Dgz[idx]);
      const float iv = sigmoid_f(gi);
      const float ov = sigmoid_f(go);
      const float fv = sigmoid_f(gf);
      const float zv = tanh_f(gz);
      const float cn = iv * zv + fv * cold[idx];
      const float hn = ov * tanh_f(cn);
      hnew[idx] = hn;
      hnewb[idx] = f2bf(hn);
    }
  }
}

// Dgz[b,u] = sum_k h_hi*W_lo + h_lo*W_hi. M=16384, N=1024, K=2048, NT=32.
__global__ __launch_bounds__(512, 2) void gemm_zcorr2(const unsigned short* __restrict__ Xb,
                                                      const unsigned short* __restrict__ Hlo,
                                                      const unsigned short* __restrict__ Wz2,
                                                      unsigned short* __restrict__ Dgz) {
  __shared__ unsigned short lds[2][2][16384];
  const int tid = threadIdx.x;
  const int lane = tid & 63, wave = tid >> 6;
  const int wm = wave & 1, wn = wave >> 1;
  const int ln = lane & 15, qlane = lane >> 4;
  const int n0 = blockIdx.x << 8, m0 = blockIdx.y << 8;
  const int sr = tid >> 3;
  const int j = ((tid & 7) - (sr & 7)) & 7;

  const unsigned short* gAX[2][2];
  const unsigned short* gAH[2][2];
  const unsigned short* gB[2][2];
#pragma unroll
  for (int hh = 0; hh < 2; ++hh)
#pragma unroll
    for (int u = 0; u < 2; ++u) {
      const int row = hh * 128 + u * 64 + sr;
      gAX[hh][u] = Xb  + (size_t)(m0 + row) * 1536 + 512 + j * 8;
      gAH[hh][u] = Hlo + (size_t)(m0 + row) * 1024 + j * 8;
      gB[hh][u]  = Wz2 + (size_t)(n0 + row) * 2048 + j * 8;
    }
  unsigned short* const dA0 = &lds[0][0][0] + (tid & ~63) * 8;
  unsigned short* const dB0 = &lds[0][1][0] + (tid & ~63) * 8;
  unsigned short* const dA1 = &lds[1][0][0] + (tid & ~63) * 8;
  unsigned short* const dB1 = &lds[1][1][0] + (tid & ~63) * 8;
  const unsigned short* const lA0 = &lds[0][0][0];
  const unsigned short* const lB0 = &lds[0][1][0];
  const unsigned short* const lA1 = &lds[1][0][0];
  const unsigned short* const lB1 = &lds[1][1][0];
  const int sl0 = ((qlane + ln) & 7) * 8;
  const int sl1 = sl0 ^ 32;
  const int aoff0 = (wm * 128 + ln) * 64 + sl0;
  const int aoff1 = (wm * 128 + ln) * 64 + sl1;
  const int boff0 = (wn * 64 + ln) * 64 + sl0;
  const int boff1 = (wn * 64 + ln) * 64 + sl1;

  f32x4 acc[8][4] = {};

  ZST_A(0, 0, dA0); ZST_A(0, 1, dA0);
  ST_B(0, 0, dB0);  ST_B(0, 1, dB0);
  ST_B(1, 0, dB1);  ST_B(1, 1, dB1);
  VM4;
  __builtin_amdgcn_s_barrier();

#pragma unroll 1
  for (int t = 0; t < 30; t += 2) {
    KTILE(lA0, lB0, ZST_A(t + 1, 0, dA1), ZST_A(t + 1, 1, dA1),
                    ST_B(t + 2, 0, dB0),  ST_B(t + 2, 1, dB0), VM4);
    KTILE(lA1, lB1, ZST_A(t + 2, 0, dA0), ZST_A(t + 2, 1, dA0),
                    ST_B(t + 3, 0, dB1),  ST_B(t + 3, 1, dB1), VM4);
  }
  KTILE(lA0, lB0, ZST_A(31, 0, dA1), ZST_A(31, 1, dA1), NOST, NOST, VM0);
  KTILE(lA1, lB1, NOST, NOST, NOST, NOST, VMNONE);

#pragma unroll
  for (int mi = 0; mi < 8; ++mi) {
#pragma unroll
    for (int r = 0; r < 4; ++r) {
      const int b = m0 + wm * 128 + mi * 16 + qlane * 4 + r;
#pragma unroll
      for (int ni = 0; ni < 4; ++ni) {
        const int n = n0 + wn * 64 + ni * 16 + ln;
        Dgz[b * 1024 + n] = f2bf(acc[mi][ni][r]);
      }
    }
  }
}

// out = h_new @ Wout^T + bout. M=16384, N=512, K=1024. (kept 128-tile: N too
// small for a full 256^2 grid — 256^2 would leave half the CUs idle)
__global__ __launch_bounds__(256) void gemm_out(const unsigned short* __restrict__ Hb,
                                                const unsigned short* __restrict__ Wo,
                                                const float* __restrict__ bout,
                                                float* __restrict__ out) {
  __shared__ unsigned short As[8192];
  __shared__ unsigned short Bs[8192];
  const int n0 = blockIdx.x * 128;
  const int m0 = blockIdx.y * 128;
  const int tid = threadIdx.x, lane = tid & 63, wave = tid >> 6;
  const unsigned short *ga[4], *gb[4];
  unsigned short *la[4], *lb[4];
#pragma unroll
  for (int u = 0; u < 4; ++u) {
    int p = u * 256 + tid;
    int r = p >> 3;
    int jj = ((p & 7) - r) & 7;
    ga[u] = Hb + (size_t)(m0 + r) * 1024 + jj * 8;
    gb[u] = Wo + (size_t)(n0 + r) * 1024 + jj * 8;
    la[u] = As + (u * 256 + (tid & ~63)) * 8;
    lb[u] = Bs + (u * 256 + (tid & ~63)) * 8;
  }
  f32x4 acc[4][4] = {};
  for (int kk = 0; kk < 16; ++kk) {
#pragma unroll
    for (int u = 0; u < 4; ++u) { stage16(ga[u], la[u]); stage16(gb[u], lb[u]); }
#pragma unroll
    for (int u = 0; u < 4; ++u) { ga[u] += 64; gb[u] += 64; }
    __syncthreads();
    mma_step64(As, Bs, acc, lane, wave);
    __syncthreads();
  }
  const int wm = wave & 1, wn = wave >> 1;
  const int ln = lane & 15, q = lane >> 4;
  float bo_[4];
#pragma unroll
  for (int ni = 0; ni < 4; ++ni) bo_[ni] = bout[n0 + wn * 64 + ni * 16 + ln];
#pragma unroll
  for (int mi = 0; mi < 4; ++mi) {
#pragma unroll
    for (int r = 0; r < 4; ++r) {
      const int b = m0 + wm * 64 + mi * 16 + q * 4 + r;
#pragma unroll
      for (int ni = 0; ni < 4; ++ni) {
        const int n = n0 + wn * 64 + ni * 16 + ln;
        out[b * 512 + n] = acc[mi][ni][r] + bo_[ni];
      }
    }
  }
}

extern "C" void kernel_launch(void* const* d_in, const int* in_sizes, int n_in,
                              void* d_out, int out_size, void* d_ws, size_t ws_size,
                              hipStream_t stream) {
  const float* inp  = (const float*)d_in[0];
  const float* h    = (const float*)d_in[1];
  const float* c    = (const float*)d_in[2];
  const float* Wx   = (const float*)d_in[3];
  const float* bx   = (const float*)d_in[4];
  const float* Wh   = (const float*)d_in[5];
  const float* Wout = (const float*)d_in[6];
  const float* bout = (const float*)d_in[7];

  float* out  = (float*)d_out;                       // [B, 512]
  float* hnew = out + (size_t)BB * OO;               // [B, 1024]

  char* ws = (char*)d_ws;
  unsigned short* Xb  = (unsigned short*)(ws);                  //  50,331,648 B
  unsigned short* Wg  = (unsigned short*)(ws + 50331648);       //  12,582,912 B
  unsigned short* Wo  = (unsigned short*)(ws + 62914560);       //   1,048,576 B
  unsigned short* Hb  = (unsigned short*)(ws + 63963136);       //  33,554,432 B
  unsigned short* Hlo = (unsigned short*)(ws + 97517568);       //  33,554,432 B
  unsigned short* Wz2 = (unsigned short*)(ws + 131072000);      //   4,194,304 B
  unsigned short* Dgz = (unsigned short*)(ws + 135266304);      //  33,554,432 B

  prep_X   <<<12288, 256, 0, stream>>>(inp, h, Xb, Hlo);
  prep_Wg  <<<3072,  256, 0, stream>>>(Wx, Wh, Wg);
  prep_Wz2 <<<1024,  256, 0, stream>>>(Wh + 3 * 1024 * 1024, Wz2);
  prep_Wout<<<256,   256, 0, stream>>>(Wout, Wo);
  gemm_zcorr2<<<dim3(4, 64),  512, 0, stream>>>(Xb, Hlo, Wz2, Dgz);
  gemm_gates2<<<dim3(16, 64), 512, 0, stream>>>(Xb, Wg, bx, c, Dgz, hnew, Hb);
  gemm_out  <<<dim3(4, 128),  256, 0, stream>>>(Hb, Wo, bout, out);
}